// Round 5
// baseline (819.383 us; speedup 1.0000x reference)
//
#include <hip/hip_runtime.h>

// ChunkedLSAttention on MI355X (gfx950).
// B=4, L=2048, D=1024, H=16, DH=64, W=128, CS=32, NCC=NCB=64, NC=128, NQ=64.
// All harness I/O f32. bf16 for all MFMA operands and bulk intermediates.
// Mask (d_in[20]) deterministic: masked iff ci-64 >= qc. rel_shift -> pos_c[64+ci-qc].

typedef unsigned short u16;
typedef __attribute__((ext_vector_type(8))) short short8;
typedef __attribute__((ext_vector_type(4))) float f32x4;

#define NEGINF -1e30f

__device__ __forceinline__ float bf2f(u16 u) {
    union { unsigned int i; float f; } v; v.i = ((unsigned int)u) << 16; return v.f;
}
__device__ __forceinline__ u16 f2bf(float f) {
    union { float fl; unsigned int i; } v; v.fl = f;
    unsigned int x = v.i;
    return (u16)((x + 0x7fffu + ((x >> 16) & 1u)) >> 16);   // RNE
}
__device__ __forceinline__ short8 ldg8(const u16* p) { return *(const short8*)p; }

// async global->LDS, 16B per lane; LDS dest = wave-uniform base + lane*16.
__device__ __forceinline__ void async16(const u16* g, u16* l) {
    __builtin_amdgcn_global_load_lds(
        (const __attribute__((address_space(1))) unsigned int*)g,
        (__attribute__((address_space(3))) unsigned int*)l, 16, 0, 0);
}

// ---------------------------------------------------------------------------
// casts
// ---------------------------------------------------------------------------
__global__ __launch_bounds__(256) void cast_f2b(const float* __restrict__ s,
                                                u16* __restrict__ d, int n4)
{
    int i = blockIdx.x * 256 + threadIdx.x;
    if (i >= n4) return;
    float4 v = ((const float4*)s)[i];
    u16* o = d + i * 4;
    o[0] = f2bf(v.x); o[1] = f2bf(v.y); o[2] = f2bf(v.z); o[3] = f2bf(v.w);
}

// 6x weight (1024x1024 f32 [k][n]) -> bf16 [n][k].  grid=(32,32,6), block 256.
__global__ __launch_bounds__(256) void cast_transpose6(
    const float* __restrict__ W0, const float* __restrict__ W1,
    const float* __restrict__ W2, const float* __restrict__ W3,
    const float* __restrict__ W4, const float* __restrict__ W5,
    u16* __restrict__ T0, u16* __restrict__ T1, u16* __restrict__ T2,
    u16* __restrict__ T3, u16* __restrict__ T4, u16* __restrict__ T5)
{
    const float* W; u16* WT;
    switch (blockIdx.z) {
        case 0: W = W0; WT = T0; break;
        case 1: W = W1; WT = T1; break;
        case 2: W = W2; WT = T2; break;
        case 3: W = W3; WT = T3; break;
        case 4: W = W4; WT = T4; break;
        default: W = W5; WT = T5; break;
    }
    __shared__ float t[32][33];
    const int bx = blockIdx.x, by = blockIdx.y;
    const int tx = threadIdx.x & 31, ty = threadIdx.x >> 5;
    #pragma unroll
    for (int p = 0; p < 4; ++p) {
        int k = by * 32 + ty + p * 8;
        t[ty + p * 8][tx] = W[(long)k * 1024 + bx * 32 + tx];
    }
    __syncthreads();
    #pragma unroll
    for (int p = 0; p < 4; ++p) {
        int n = ty + p * 8;
        WT[((long)(bx * 32 + n)) * 1024 + by * 32 + tx] = f2bf(t[tx][n]);
    }
}

// ---------------------------------------------------------------------------
// GEMM (m97-style): C = A(bf16 MxK) @ Bt^T (Bt bf16 NxK) * scale + bias.
// Tile 128x128, BK=32, 4 waves. grid=(M/128, N/128, nbatch).
// ---------------------------------------------------------------------------
__global__ __launch_bounds__(256) void gemm_bt(
    const u16* __restrict__ A, long a_bstride,
    const u16* __restrict__ Bt,
    float* __restrict__ Cf, u16* __restrict__ Cb, long c_bstride,
    int N, int K, const float* __restrict__ bias, float scale)
{
    const int tid = threadIdx.x;
    const int bm = blockIdx.x, bn = blockIdx.y, bz = blockIdx.z;
    A += (long)bz * a_bstride;
    const long coff = (long)bz * c_bstride;

    __shared__ __align__(16) u16 As[128 * 32];
    __shared__ __align__(16) u16 Bs[128 * 32];

    const int lane = tid & 63, wv = tid >> 6;
    const int l15 = lane & 15, quad = lane >> 4;
    const int wm = (wv & 1) * 64, wn = (wv >> 1) * 64;

    f32x4 acc[4][4];
    #pragma unroll
    for (int i = 0; i < 4; ++i)
        #pragma unroll
        for (int j = 0; j < 4; ++j) acc[i][j] = (f32x4){0.f, 0.f, 0.f, 0.f};

    const int srow = wv * 32 + (lane >> 2);
    const int scol = (lane & 3) * 8;
    const u16* a_src  = A  + (long)(bm * 128 + srow) * K + scol;
    const u16* a_src2 = a_src + (long)16 * K;
    const u16* b_src  = Bt + (long)(bn * 128 + srow) * K + scol;
    const u16* b_src2 = b_src + (long)16 * K;
    u16* lA0 = &As[(wv * 32) * 32];
    u16* lA1 = &As[(wv * 32 + 16) * 32];
    u16* lB0 = &Bs[(wv * 32) * 32];
    u16* lB1 = &Bs[(wv * 32 + 16) * 32];

    for (int k0 = 0; k0 < K; k0 += 32) {
        async16(a_src, lA0); async16(a_src2, lA1);
        async16(b_src, lB0); async16(b_src2, lB1);
        a_src += 32; a_src2 += 32; b_src += 32; b_src2 += 32;
        __syncthreads();
        short8 af[4], bfr[4];
        #pragma unroll
        for (int i = 0; i < 4; ++i)
            af[i] = *(const short8*)&As[(wm + i * 16 + l15) * 32 + quad * 8];
        #pragma unroll
        for (int j = 0; j < 4; ++j)
            bfr[j] = *(const short8*)&Bs[(wn + j * 16 + l15) * 32 + quad * 8];
        #pragma unroll
        for (int i = 0; i < 4; ++i)
            #pragma unroll
            for (int j = 0; j < 4; ++j)
                acc[i][j] = __builtin_amdgcn_mfma_f32_16x16x32_bf16(af[i], bfr[j], acc[i][j], 0, 0, 0);
        __syncthreads();
    }

    #pragma unroll
    for (int i = 0; i < 4; ++i) {
        #pragma unroll
        for (int j = 0; j < 4; ++j) {
            int col = bn * 128 + wn + j * 16 + l15;
            float bsv = bias ? bias[col] : 0.f;
            #pragma unroll
            for (int r = 0; r < 4; ++r) {
                int row = bm * 128 + wm + i * 16 + quad * 4 + r;
                float v = acc[i][j][r] * scale + bsv;
                long idx = coff + (long)row * N + col;
                if (Cf) Cf[idx] = v;
                if (Cb) Cb[idx] = f2bf(v);
            }
        }
    }
}

// ---------------------------------------------------------------------------
// Per-chunk head scores (+softmax over 32 rows) and optional compress of src.
// src is bf16. grid=(64, B), block 256.
// ---------------------------------------------------------------------------
__global__ __launch_bounds__(256) void scores_compress(
    const u16* __restrict__ src, long src_bstride,
    const float* __restrict__ Wd, const float* __restrict__ bd,
    u16* __restrict__ out_comp, long comp_bstride,
    float* __restrict__ out_sc, long sc_bstride)
{
    const int c = blockIdx.x, b = blockIdx.y;
    const int tid = threadIdx.x;

    __shared__ __align__(16) u16 srcs[32][1032];
    __shared__ float s_sm[32][16];

    const u16* sb = src + (long)b * src_bstride + (long)c * 32 * 1024;
    for (int e = tid; e < 4096; e += 256) {
        int flat = e * 8;
        int row = flat >> 10, col = flat & 1023;
        *(short8*)&srcs[row][col] = ldg8(sb + (long)row * 1024 + col);
    }
    __syncthreads();

    {
        int i = tid >> 3;
        int hd0 = (tid & 7) * 2;
        float acc0 = bd[hd0], acc1 = bd[hd0 + 1];
        for (int d = 0; d < 1024; ++d) {
            float xv = bf2f(srcs[i][d]);
            float2 wp = *(const float2*)(Wd + d * 16 + hd0);
            acc0 += xv * wp.x;
            acc1 += xv * wp.y;
        }
        s_sm[i][hd0] = acc0;
        s_sm[i][hd0 + 1] = acc1;
    }
    __syncthreads();

    if (tid < 16) {
        int hd = tid;
        float m = NEGINF;
        for (int i = 0; i < 32; ++i) m = fmaxf(m, s_sm[i][hd]);
        float s = 0.f;
        for (int i = 0; i < 32; ++i) s += __expf(s_sm[i][hd] - m);
        float inv = 1.f / s;
        for (int i = 0; i < 32; ++i) s_sm[i][hd] = __expf(s_sm[i][hd] - m) * inv;
    }
    __syncthreads();

    if (out_sc) {
        for (int idx = tid; idx < 512; idx += 256) {
            int hd = idx >> 5, i = idx & 31;
            out_sc[(long)b * sc_bstride + ((long)hd * 64 + c) * 32 + i] = s_sm[i][hd];
        }
    }
    if (out_comp) {
        #pragma unroll
        for (int p = 0; p < 4; ++p) {
            int j = tid + p * 256;
            int hd = j >> 6;
            float acc = 0.f;
            for (int i = 0; i < 32; ++i) acc += s_sm[i][hd] * bf2f(srcs[i][j]);
            out_comp[(long)b * comp_bstride + (long)c * 1024 + j] = f2bf(acc);
        }
    }
}

// ---------------------------------------------------------------------------
// Compress bf16 k_bp/v_bp with block scores, LN -> k_comp rows 64..127 (bf16)
// and vcT cols 64..127 (bf16 transposed (B,1024,128)). grid=(64,B).
// ---------------------------------------------------------------------------
__global__ __launch_bounds__(256) void compress_kv_ln(
    const u16* __restrict__ kbp, const u16* __restrict__ vbp,
    const float* __restrict__ sc,
    const float* __restrict__ g, const float* __restrict__ be,
    u16* __restrict__ k_comp, u16* __restrict__ vcT)
{
    const int c = blockIdx.x, b = blockIdx.y;
    const int tid = threadIdx.x;
    const int lane = tid & 63, wv = tid >> 6;

    __shared__ float scw[16][32];
    __shared__ float red[4][4];

    for (int idx = tid; idx < 512; idx += 256) {
        int hd = idx >> 5, i = idx & 31;
        scw[hd][i] = sc[((long)(b * 16 + hd) * 64 + c) * 32 + i];
    }
    __syncthreads();

    float xk[4], xv[4];
    #pragma unroll
    for (int p = 0; p < 4; ++p) {
        int j = tid + p * 256;
        int hd = j >> 6;
        float ak = 0.f, av = 0.f;
        for (int i = 0; i < 32; ++i) {
            float w = scw[hd][i];
            long off = ((long)b * 2048 + c * 32 + i) * 1024 + j;
            ak += w * bf2f(kbp[off]);
            av += w * bf2f(vbp[off]);
        }
        xk[p] = ak; xv[p] = av;
    }
    float sk = 0.f, qk = 0.f, sv = 0.f, qv = 0.f;
    #pragma unroll
    for (int p = 0; p < 4; ++p) { sk += xk[p]; qk += xk[p]*xk[p]; sv += xv[p]; qv += xv[p]*xv[p]; }
    for (int off = 32; off; off >>= 1) {
        sk += __shfl_xor(sk, off); qk += __shfl_xor(qk, off);
        sv += __shfl_xor(sv, off); qv += __shfl_xor(qv, off);
    }
    if (lane == 0) { red[0][wv] = sk; red[1][wv] = qk; red[2][wv] = sv; red[3][wv] = qv; }
    __syncthreads();
    sk = red[0][0] + red[0][1] + red[0][2] + red[0][3];
    qk = red[1][0] + red[1][1] + red[1][2] + red[1][3];
    sv = red[2][0] + red[2][1] + red[2][2] + red[2][3];
    qv = red[3][0] + red[3][1] + red[3][2] + red[3][3];
    const float inv_n = 1.f / 1024.f;
    float mk = sk * inv_n, mv = sv * inv_n;
    float ik = rsqrtf(fmaxf(qk * inv_n - mk * mk, 0.f) + 1e-5f);
    float iv = rsqrtf(fmaxf(qv * inv_n - mv * mv, 0.f) + 1e-5f);
    #pragma unroll
    for (int p = 0; p < 4; ++p) {
        int j = tid + p * 256;
        k_comp[((long)b * 128 + 64 + c) * 1024 + j] = f2bf((xk[p] - mk) * ik * g[j] + be[j]);
        vcT[((long)b * 1024 + j) * 128 + 64 + c]   = f2bf((xv[p] - mv) * iv * g[j] + be[j]);
    }
}

// ---------------------------------------------------------------------------
// LN of cache-compressed K and V (bf16 src) -> k_comp rows 0..63 and vcT cols
// 0..63.  grid.x = B*64, block 256.
// ---------------------------------------------------------------------------
__global__ __launch_bounds__(256) void ln_kv(
    const u16* __restrict__ ksrc, const u16* __restrict__ vsrc,
    const float* __restrict__ g, const float* __restrict__ be,
    u16* __restrict__ k_comp, u16* __restrict__ vcT)
{
    const int gr = blockIdx.x;
    const int b = gr >> 6, r = gr & 63;
    const u16* ks = ksrc + (long)(b * 64 + r) * 1024;
    const u16* vs = vsrc + (long)(b * 64 + r) * 1024;
    const int tid = threadIdx.x;
    const int lane = tid & 63, wv = tid >> 6;

    __shared__ float red[4][4];
    float xk[4], xv[4];
    float sk = 0.f, qk = 0.f, sv = 0.f, qv = 0.f;
    #pragma unroll
    for (int p = 0; p < 4; ++p) {
        xk[p] = bf2f(ks[tid + p * 256]);
        xv[p] = bf2f(vs[tid + p * 256]);
        sk += xk[p]; qk += xk[p]*xk[p]; sv += xv[p]; qv += xv[p]*xv[p];
    }
    for (int off = 32; off; off >>= 1) {
        sk += __shfl_xor(sk, off); qk += __shfl_xor(qk, off);
        sv += __shfl_xor(sv, off); qv += __shfl_xor(qv, off);
    }
    if (lane == 0) { red[0][wv] = sk; red[1][wv] = qk; red[2][wv] = sv; red[3][wv] = qv; }
    __syncthreads();
    sk = red[0][0] + red[0][1] + red[0][2] + red[0][3];
    qk = red[1][0] + red[1][1] + red[1][2] + red[1][3];
    sv = red[2][0] + red[2][1] + red[2][2] + red[2][3];
    qv = red[3][0] + red[3][1] + red[3][2] + red[3][3];
    const float inv_n = 1.f / 1024.f;
    float mk = sk * inv_n, mv = sv * inv_n;
    float ik = rsqrtf(fmaxf(qk * inv_n - mk * mk, 0.f) + 1e-5f);
    float iv = rsqrtf(fmaxf(qv * inv_n - mv * mv, 0.f) + 1e-5f);
    #pragma unroll
    for (int p = 0; p < 4; ++p) {
        int j = tid + p * 256;
        k_comp[((long)b * 128 + r) * 1024 + j] = f2bf((xk[p] - mk) * ik * g[j] + be[j]);
        vcT[((long)b * 1024 + j) * 128 + r]   = f2bf((xv[p] - mv) * iv * g[j] + be[j]);
    }
}

// ---------------------------------------------------------------------------
// Window LN stats for K and V concat rows (bf16 srcs). grid.x = B*2176.
// ---------------------------------------------------------------------------
__global__ __launch_bounds__(256) void row_stats_kv(
    const u16* __restrict__ kcw, const u16* __restrict__ vcw,
    const u16* __restrict__ kbp, const u16* __restrict__ vbp,
    float2* __restrict__ st_kw, float2* __restrict__ st_vw)
{
    const int gr = blockIdx.x;
    const int b = gr / 2176, t = gr % 2176;
    const u16* ks; const u16* vs;
    if (t < 128) {
        ks = kcw + (long)(b * 128 + t) * 1024;
        vs = vcw + (long)(b * 128 + t) * 1024;
    } else {
        ks = kbp + ((long)b * 2048 + t - 128) * 1024;
        vs = vbp + ((long)b * 2048 + t - 128) * 1024;
    }
    const int tid = threadIdx.x;
    const int lane = tid & 63, wv = tid >> 6;

    __shared__ float red[4][4];
    float sk = 0.f, qk = 0.f, sv = 0.f, qv = 0.f;
    #pragma unroll
    for (int p = 0; p < 4; ++p) {
        float xk = bf2f(ks[tid + p * 256]);
        float xv = bf2f(vs[tid + p * 256]);
        sk += xk; qk += xk*xk; sv += xv; qv += xv*xv;
    }
    for (int off = 32; off; off >>= 1) {
        sk += __shfl_xor(sk, off); qk += __shfl_xor(qk, off);
        sv += __shfl_xor(sv, off); qv += __shfl_xor(qv, off);
    }
    if (lane == 0) { red[0][wv] = sk; red[1][wv] = qk; red[2][wv] = sv; red[3][wv] = qv; }
    __syncthreads();
    if (tid == 0) {
        sk = red[0][0] + red[0][1] + red[0][2] + red[0][3];
        qk = red[1][0] + red[1][1] + red[1][2] + red[1][3];
        sv = red[2][0] + red[2][1] + red[2][2] + red[2][3];
        qv = red[3][0] + red[3][1] + red[3][2] + red[3][3];
        const float inv_n = 1.f / 1024.f;
        float mk = sk * inv_n, mv = sv * inv_n;
        st_kw[(long)b * 2176 + t] = make_float2(mk, rsqrtf(fmaxf(qk * inv_n - mk * mk, 0.f) + 1e-5f));
        st_vw[(long)b * 2176 + t] = make_float2(mv, rsqrtf(fmaxf(qv * inv_n - mv * mv, 0.f) + 1e-5f));
    }
}

// ---------------------------------------------------------------------------
// Materialize window K (bf16 (B,2176,1024)) and V^T (bf16 (B,1024,2176),
// col = concat_row - 1).  bf16 srcs.  grid=(34, 16, B).
// ---------------------------------------------------------------------------
__global__ __launch_bounds__(256) void win_apply(
    const u16* __restrict__ kcw, const u16* __restrict__ vcw,
    const u16* __restrict__ kbp, const u16* __restrict__ vbp,
    const float2* __restrict__ st_kw, const float2* __restrict__ st_vw,
    const float* __restrict__ g_w, const float* __restrict__ b_w,
    u16* __restrict__ kwin, u16* __restrict__ vwinT)
{
    const int tt = blockIdx.x, dc = blockIdx.y, b = blockIdx.z;
    const int t0 = tt * 64, d0 = dc * 64;
    const int tid = threadIdx.x;

    __shared__ u16 vt[64][74];

    const int r = tid >> 2;
    const int dsub = (tid & 3) * 16;
    const int t = t0 + r;
    const u16* ks; const u16* vs;
    if (t < 128) {
        ks = kcw + (long)(b * 128 + t) * 1024;
        vs = vcw + (long)(b * 128 + t) * 1024;
    } else {
        ks = kbp + ((long)b * 2048 + t - 128) * 1024;
        vs = vbp + ((long)b * 2048 + t - 128) * 1024;
    }
    float2 sk = st_kw[(long)b * 2176 + t];
    float2 sv = st_vw[(long)b * 2176 + t];
    #pragma unroll
    for (int j = 0; j < 16; j += 8) {
        int d = d0 + dsub + j;
        short8 kv8 = ldg8(ks + d);
        short8 vv8 = ldg8(vs + d);
        short8 ko;
        #pragma unroll
        for (int e = 0; e < 8; ++e) {
            float ge = g_w[d + e], bbe = b_w[d + e];
            ko[e] = (short)f2bf((bf2f((u16)kv8[e]) - sk.x) * sk.y * ge + bbe);
            vt[r][dsub + j + e] = f2bf((bf2f((u16)vv8[e]) - sv.x) * sv.y * ge + bbe);
        }
        *(short8*)&kwin[((long)b * 2176 + t) * 1024 + d] = ko;
    }
    __syncthreads();
    #pragma unroll
    for (int pass = 0; pass < 16; ++pass) {
        int dd = (tid >> 6) + pass * 4;
        int rr = tid & 63;
        int crow = t0 + rr;
        if (crow >= 1)
            vwinT[((long)b * 1024 + d0 + dd) * 2176 + crow - 1] = vt[rr][dd];
    }
}

// ---------------------------------------------------------------------------
// Fused MFMA attention: one block per (qc, h, b), 256 thr = 4 waves.
// All score B-frags prefetched at entry; V prefetched before softmax;
// register softmax (1 pass, 3 shuffles); 5 barriers total.
// ---------------------------------------------------------------------------
__global__ __launch_bounds__(256) void attention(
    const u16* __restrict__ qb,     // (B,2048,1024) bf16, already /8
    const u16* __restrict__ kcb,    // (B,128,1024) bf16
    const u16* __restrict__ vcT,    // (B,1024,128) bf16 transposed
    const u16* __restrict__ kwb,    // (B,2176,1024) bf16
    const u16* __restrict__ vwT,    // (B,1024,2176) bf16 transposed, col=row-1
    const u16* __restrict__ pcb,    // (128,1024) bf16
    const u16* __restrict__ ptb,    // (128,1024) bf16
    const float* __restrict__ r_w,  // (16,64)
    const float* __restrict__ r_r,
    u16* __restrict__ attn_o)       // (B,2048,1024) bf16
{
    const int bx = blockIdx.x;
    const int qc = ((bx & 7) << 3) | (bx >> 3);   // XCD-contiguous qc groups
    const int h = blockIdx.y, b = blockIdx.z;
    const int l0 = qc * 32;
    const int tid = threadIdx.x;
    const int lane = tid & 63, wv = tid >> 6;
    const int l15 = lane & 15, quad = lane >> 4;

    __shared__ __align__(16) float L[32 * 258];     // logits, stride 258
    __shared__ __align__(16) char uni[19456];       // qa[3][32][72] | Pc[32][136]+Pw[32][168]
    u16 (*qa)[32][72] = (u16 (*)[32][72])uni;
    u16* Pc = (u16*)uni;
    u16* Pw = (u16*)(uni + 8704);

    // ---- prefetch ALL score-phase B fragments ----
    short8 pf_kc[2][2], pf_pc[2][2], pf_pt[2][2], pf_kw[3][2];
    #pragma unroll
    for (int ti = 0; ti < 2; ++ti) {
        int ci = (wv * 2 + ti) * 16 + l15;
        int p = 64 + ci - qc; if (p > 127) p = 127;
        #pragma unroll
        for (int kc = 0; kc < 2; ++kc) {
            pf_kc[ti][kc] = ldg8(kcb + ((long)(b * 128 + ci)) * 1024 + h * 64 + kc * 32 + quad * 8);
            pf_pc[ti][kc] = ldg8(pcb + (long)p * 1024 + h * 64 + kc * 32 + quad * 8);
            pf_pt[ti][kc] = ldg8(ptb + (long)ci * 1024 + h * 64 + kc * 32 + quad * 8);
        }
    }
    int nts[3]; int nw = 0;
    for (int nt = wv; nt < 10; nt += 4) nts[nw++] = nt;
    for (int i = 0; i < nw; ++i) {
        int t = nts[i] * 16 + l15;
        int row = l0 + 1 + t; if (row > 2175) row = 2175;
        #pragma unroll
        for (int kc = 0; kc < 2; ++kc)
            pf_kw[i][kc] = ldg8(kwb + ((long)(b * 2176 + row)) * 1024 + h * 64 + kc * 32 + quad * 8);
    }

    // ---- stage q (vectorized) ----
    {
        int r = tid >> 3, d0 = (tid & 7) * 8;
        short8 qv = ldg8(qb + ((long)(b * 2048 + l0 + r)) * 1024 + h * 64 + d0);
        float4 rw0 = *(const float4*)(r_w + h * 64 + d0);
        float4 rw1 = *(const float4*)(r_w + h * 64 + d0 + 4);
        float4 rr0 = *(const float4*)(r_r + h * 64 + d0);
        float4 rr1 = *(const float4*)(r_r + h * 64 + d0 + 4);
        float rwv[8] = {rw0.x, rw0.y, rw0.z, rw0.w, rw1.x, rw1.y, rw1.z, rw1.w};
        float rrv[8] = {rr0.x, rr0.y, rr0.z, rr0.w, rr1.x, rr1.y, rr1.z, rr1.w};
        short8 q1, q2;
        #pragma unroll
        for (int j = 0; j < 8; ++j) {
            float qf = bf2f((u16)qv[j]);
            q1[j] = (short)f2bf(qf + rwv[j]);
            q2[j] = (short)f2bf(qf + rrv[j]);
        }
        *(short8*)&qa[0][r][d0] = qv;
        *(short8*)&qa[1][r][d0] = q1;
        *(short8*)&qa[2][r][d0] = q2;
    }
    __syncthreads();                                            // B1

    // ---- S_c: q·k_comp + q·pos_c ----
    #pragma unroll
    for (int ti = 0; ti < 2; ++ti) {
        int n0 = (wv * 2 + ti) * 16;
        int ci = n0 + l15;
        f32x4 a0 = {0.f,0.f,0.f,0.f}, a1 = {0.f,0.f,0.f,0.f};
        if (n0 < 64 + qc) {
            #pragma unroll
            for (int kc = 0; kc < 2; ++kc) {
                int k0 = kc * 32;
                short8 fa0 = *(const short8*)&qa[0][l15][k0 + quad * 8];
                short8 fa1 = *(const short8*)&qa[0][16 + l15][k0 + quad * 8];
                a0 = __builtin_amdgcn_mfma_f32_16x16x32_bf16(fa0, pf_kc[ti][kc], a0, 0, 0, 0);
                a0 = __builtin_amdgcn_mfma_f32_16x16x32_bf16(fa0, pf_pc[ti][kc], a0, 0, 0, 0);
                a1 = __builtin_amdgcn_mfma_f32_16x16x32_bf16(fa1, pf_kc[ti][kc], a1, 0, 0, 0);
                a1 = __builtin_amdgcn_mfma_f32_16x16x32_bf16(fa1, pf_pc[ti][kc], a1, 0, 0, 0);
            }
        }
        bool msk = (ci >= 64 + qc);
        #pragma unroll
        for (int r = 0; r < 4; ++r) {
            L[(quad * 4 + r) * 258 + ci]      = msk ? NEGINF : a0[r];
            L[(16 + quad * 4 + r) * 258 + ci] = msk ? NEGINF : a1[r];
        }
    }

    // ---- S2: (q+r_r)·pos_t ----
    #pragma unroll
    for (int ti = 0; ti < 2; ++ti) {
        int w = (wv * 2 + ti) * 16 + l15;
        f32x4 a0 = {0.f,0.f,0.f,0.f}, a1 = {0.f,0.f,0.f,0.f};
        #pragma unroll
        for (int kc = 0; kc < 2; ++kc) {
            int k0 = kc * 32;
            short8 fa0 = *(const short8*)&qa[2][l15][k0 + quad * 8];
            short8 fa1 = *(const short8*)&qa[2][16 + l15][k0 + quad * 8];
            a0 = __builtin_amdgcn_mfma_f32_16x16x32_bf16(fa0, pf_pt[ti][kc], a0, 0, 0, 0);
            a1 = __builtin_amdgcn_mfma_f32_16x16x32_bf16(fa1, pf_pt[ti][kc], a1, 0, 0, 0);
        }
        #pragma unroll
        for (int r = 0; r < 4; ++r) {
            L[(quad * 4 + r) * 258 + 128 + w]      = a0[r];
            L[(16 + quad * 4 + r) * 258 + 128 + w] = a1[r];
        }
    }

    // ---- S1: (q+r_w)·k_win -> regs ----
    f32x4 s1a[3], s1b[3];
    for (int i = 0; i < nw; ++i) {
        f32x4 a0 = {0.f,0.f,0.f,0.f}, a1 = {0.f,0.f,0.f,0.f};
        #pragma unroll
        for (int kc = 0; kc < 2; ++kc) {
            int k0 = kc * 32;
            short8 fa0 = *(const short8*)&qa[1][l15][k0 + quad * 8];
            short8 fa1 = *(const short8*)&qa[1][16 + l15][k0 + quad * 8];
            a0 = __builtin_amdgcn_mfma_f32_16x16x32_bf16(fa0, pf_kw[i][kc], a0, 0, 0, 0);
            a1 = __builtin_amdgcn_mfma_f32_16x16x32_bf16(fa1, pf_kw[i][kc], a1, 0, 0, 0);
        }
        s1a[i] = a0; s1b[i] = a1;
    }
    __syncthreads();                                            // B2

    // ---- band add: L[row][128 + (t-row)] += S1 ----
    for (int i = 0; i < nw; ++i) {
        int t = nts[i] * 16 + l15;
        #pragma unroll
        for (int r = 0; r < 4; ++r) {
            int r0 = quad * 4 + r;
            int w0 = t - r0;
            if (w0 >= 0 && w0 < 128) L[r0 * 258 + 128 + w0] += s1a[i][r];
            int r1 = 16 + quad * 4 + r;
            int w1 = t - r1;
            if (w1 >= 0 && w1 < 128) L[r1 * 258 + 128 + w1] += s1b[i][r];
        }
    }
    __syncthreads();                                            // B3

    // ---- V prefetch (flies during softmax) ----
    short8 pf_vc[4], pf_vw[5];
    const int n0d = wv * 16;
    #pragma unroll
    for (int kc = 0; kc < 4; ++kc)
        pf_vc[kc] = ldg8(vcT + ((long)(b * 1024 + h * 64 + n0d + l15)) * 128 + kc * 32 + quad * 8);
    #pragma unroll
    for (int kc = 0; kc < 5; ++kc)
        pf_vw[kc] = ldg8(vwT + ((long)(b * 1024 + h * 64 + n0d + l15)) * 2176 + l0 + kc * 32 + quad * 8);

    // ---- softmax: thread = (row, 32-col strip), all values in regs ----
    {
        const int sr = tid >> 3;          // row 0..31
        const int sc8 = tid & 7;          // strip
        float ev[32];
        float mx = NEGINF;
        #pragma unroll
        for (int ii = 0; ii < 32; ++ii) {
            int i = (ii + sc8 * 4) & 31;  // rotate to spread banks
            float v = L[sr * 258 + sc8 * 32 + i];
            ev[ii] = v;
            mx = fmaxf(mx, v);
        }
        mx = fmaxf(mx, __shfl_xor(mx, 1));
        mx = fmaxf(mx, __shfl_xor(mx, 2));
        mx = fmaxf(mx, __shfl_xor(mx, 4));
        float sum = 0.f;
        #pragma unroll
        for (int ii = 0; ii < 32; ++ii) { ev[ii] = __expf(ev[ii] - mx); sum += ev[ii]; }
        sum += __shfl_xor(sum, 1);
        sum += __shfl_xor(sum, 2);
        sum += __shfl_xor(sum, 4);
        float inv = 1.f / sum;
        if (sc8 < 4) {
            #pragma unroll
            for (int ii = 0; ii < 32; ++ii) {
                int col = sc8 * 32 + ((ii + sc8 * 4) & 31);
                Pc[sr * 136 + col] = f2bf(ev[ii] * inv);
            }
        } else {
            int wbase = (sc8 - 4) * 32;
            if (sc8 == 4) for (int t = 0; t < sr; ++t) Pw[sr * 168 + t] = 0;
            if (sc8 == 7) for (int t = sr + 128; t < 168; ++t) Pw[sr * 168 + t] = 0;
            #pragma unroll
            for (int ii = 0; ii < 32; ++ii) {
                int w = wbase + ((ii + sc8 * 4) & 31);
                Pw[sr * 168 + sr + w] = f2bf(ev[ii] * inv);
            }
        }
    }
    __syncthreads();                                            // B4

    // ---- PV: wave wv -> d-tile wv*16 ----
    f32x4 o0 = {0.f,0.f,0.f,0.f}, o1 = {0.f,0.f,0.f,0.f};
    #pragma unroll
    for (int kc = 0; kc < 4; ++kc) {           // compressed, K=128
        int k0 = kc * 32;
        short8 av0 = *(const short8*)&Pc[l15 * 136 + k0 + quad * 8];
        short8 av1 = *(const short8*)&Pc[(16 + l15) * 136 + k0 + quad * 8];
        o0 = __builtin_amdgcn_mfma_f32_16x16x32_bf16(av0, pf_vc[kc], o0, 0, 0, 0);
        o1 = __builtin_amdgcn_mfma_f32_16x16x32_bf16(av1, pf_vc[kc], o1, 0, 0, 0);
    }
    #pragma unroll
    for (int kc = 0; kc < 5; ++kc) {           // windowed, K=160 banded
        int k0 = kc * 32;
        short8 av0 = *(const short8*)&Pw[l15 * 168 + k0 + quad * 8];
        short8 av1 = *(const short8*)&Pw[(16 + l15) * 168 + k0 + quad * 8];
        o0 = __builtin_amdgcn_mfma_f32_16x16x32_bf16(av0, pf_vw[kc], o0, 0, 0, 0);
        o1 = __builtin_amdgcn_mfma_f32_16x16x32_bf16(av1, pf_vw[kc], o1, 0, 0, 0);
    }
    #pragma unroll
    for (int r = 0; r < 4; ++r) {
        int r0 = quad * 4 + r, r1 = 16 + quad * 4 + r;
        attn_o[((long)(b * 2048 + l0 + r0)) * 1024 + h * 64 + n0d + l15] = f2bf(o0[r]);
        attn_o[((long)(b * 2048 + l0 + r1)) * 1024 + h * 64 + n0d + l15] = f2bf(o1[r]);
    }
}

// ---------------------------------------------------------------------------
extern "C" void kernel_launch(void* const* d_in, const int* in_sizes, int n_in,
                              void* d_out, int out_size, void* d_ws, size_t ws_size,
                              hipStream_t stream)
{
    (void)in_sizes; (void)n_in; (void)out_size; (void)ws_size;

    const float* h       = (const float*)d_in[0];
    const float* h_cache = (const float*)d_in[1];
    const float* key_pe  = (const float*)d_in[2];
    const float* pos_w   = (const float*)d_in[3];
    const float* Wq      = (const float*)d_in[4];
    const float* Wk      = (const float*)d_in[5];
    const float* Wv      = (const float*)d_in[6];
    const float* Wo      = (const float*)d_in[7];
    const float* Wd      = (const float*)d_in[8];
    const float* bd      = (const float*)d_in[9];
    const float* Wr      = (const float*)d_in[10];
    const float* br      = (const float*)d_in[11];
    const float* Wrc     = (const float*)d_in[12];
    const float* brc     = (const float*)d_in[13];
    const float* r_r     = (const float*)d_in[14];
    const float* r_w     = (const float*)d_in[15];
    const float* g_d     = (const float*)d_in[16];
    const float* b_d     = (const float*)d_in[17];
    const float* g_w     = (const float*)d_in[18];
    const float* b_w     = (const float*)d_in[19];

    char* ws = (char*)d_ws;
    size_t off = 0;
    auto alloc = [&](size_t bytes) -> void* {
        void* p = ws + off; off += (bytes + 255) & ~(size_t)255; return p;
    };
    u16* hB    = (u16*)alloc((size_t)8192 * 1024 * 2);
    u16* hcB   = (u16*)alloc((size_t)8192 * 1024 * 2);
    u16* WqT   = (u16*)alloc((size_t)1024 * 1024 * 2);
    u16* WkT   = (u16*)alloc((size_t)1024 * 1024 * 2);
    u16* WvT   = (u16*)alloc((size_t)1024 * 1024 * 2);
    u16* WoT   = (u16*)alloc((size_t)1024 * 1024 * 2);
    u16* WrT   = (u16*)alloc((size_t)1024 * 1024 * 2);
    u16* WrcT  = (u16*)alloc((size_t)1024 * 1024 * 2);
    u16* pwB   = (u16*)alloc((size_t)128 * 1024 * 2);
    u16* kpeB  = (u16*)alloc((size_t)128 * 1024 * 2);
    u16*   q_ws   = (u16*)alloc((size_t)8192 * 1024 * 2);
    u16*   kbpB   = (u16*)alloc((size_t)8192 * 1024 * 2);
    u16*   vbpB   = (u16*)alloc((size_t)8192 * 1024 * 2);
    u16*   attn_o = (u16*)alloc((size_t)8192 * 1024 * 2);
    u16*   kcwB   = (u16*)alloc((size_t)4 * 128 * 1024 * 2);
    u16*   vcwB   = (u16*)alloc((size_t)4 * 128 * 1024 * 2);
    u16*   hcm    = (u16*)alloc((size_t)4 * 64 * 1024 * 2);
    u16*   kc_raw = (u16*)alloc((size_t)4 * 64 * 1024 * 2);
    u16*   vc_raw = (u16*)alloc((size_t)4 * 64 * 1024 * 2);
    float* sc_blk = (float*)alloc((size_t)4 * 16 * 64 * 32 * 4);
    u16*   k_comp = (u16*)alloc((size_t)4 * 128 * 1024 * 2);
    u16*   vcT    = (u16*)alloc((size_t)4 * 1024 * 128 * 2);
    float2* st_kw = (float2*)alloc((size_t)4 * 2176 * 8);
    float2* st_vw = (float2*)alloc((size_t)4 * 2176 * 8);
    u16*   pos_tb = (u16*)alloc((size_t)128 * 1024 * 2);
    u16*   pos_cb = (u16*)alloc((size_t)128 * 1024 * 2);
    u16*   kwin   = (u16*)alloc((size_t)4 * 2176 * 1024 * 2);
    u16*   vwinT  = (u16*)alloc((size_t)4 * 1024 * 2176 * 2 + 256);

    const dim3 blk(256);

    // casts
    cast_f2b<<<dim3(8192), blk, 0, stream>>>(h, hB, 2097152);
    cast_f2b<<<dim3(8192), blk, 0, stream>>>(h_cache, hcB, 2097152);
    cast_transpose6<<<dim3(32,32,6), blk, 0, stream>>>(Wq, Wk, Wv, Wo, Wr, Wrc,
                                                       WqT, WkT, WvT, WoT, WrT, WrcT);
    cast_f2b<<<dim3(128), blk, 0, stream>>>(pos_w, pwB, 32768);
    cast_f2b<<<dim3(128), blk, 0, stream>>>(key_pe, kpeB, 32768);

    // projections (bf16 out)
    gemm_bt<<<dim3(64,8,1), blk, 0, stream>>>(hB, 0, WqT, nullptr, q_ws, 0, 1024, 1024, nullptr, 0.125f);
    gemm_bt<<<dim3(64,8,1), blk, 0, stream>>>(hB, 0, WkT, nullptr, kbpB, 0, 1024, 1024, nullptr, 1.f);
    gemm_bt<<<dim3(64,8,1), blk, 0, stream>>>(hB, 0, WvT, nullptr, vbpB, 0, 1024, 1024, nullptr, 1.f);
    gemm_bt<<<dim3(1,8,4), blk, 0, stream>>>(hcB + (long)1920*1024, (long)2048*1024, WkT,
                                             nullptr, kcwB, (long)128*1024, 1024, 1024, nullptr, 1.f);
    gemm_bt<<<dim3(1,8,4), blk, 0, stream>>>(hcB + (long)1920*1024, (long)2048*1024, WvT,
                                             nullptr, vcwB, (long)128*1024, 1024, 1024, nullptr, 1.f);

    // scores + compress
    scores_compress<<<dim3(64,4), blk, 0, stream>>>(hcB, (long)2048*1024, Wd, bd,
                                                    hcm, (long)64*1024, nullptr, 0);
    scores_compress<<<dim3(64,4), blk, 0, stream>>>(hB, (long)2048*1024, Wd, bd,
                                                    nullptr, 0, sc_blk, (long)16*64*32);
    gemm_bt<<<dim3(2,8,1), blk, 0, stream>>>(hcm, 0, WkT, nullptr, kc_raw, 0, 1024, 1024, nullptr, 1.f);
    gemm_bt<<<dim3(2,8,1), blk, 0, stream>>>(hcm, 0, WvT, nullptr, vc_raw, 0, 1024, 1024, nullptr, 1.f);

    compress_kv_ln<<<dim3(64,4), blk, 0, stream>>>(kbpB, vbpB, sc_blk, g_d, b_d, k_comp, vcT);
    ln_kv<<<dim3(256), blk, 0, stream>>>(kc_raw, vc_raw, g_d, b_d, k_comp, vcT);

    // window LN
    row_stats_kv<<<dim3(8704), blk, 0, stream>>>(kcwB, vcwB, kbpB, vbpB, st_kw, st_vw);
    win_apply<<<dim3(34,16,4), blk, 0, stream>>>(kcwB, vcwB, kbpB, vbpB, st_kw, st_vw, g_w, b_w, kwin, vwinT);

    // positional projections
    gemm_bt<<<dim3(1,8,1), blk, 0, stream>>>(pwB,  0, WrT,  nullptr, pos_tb, 0, 1024, 1024, br,  1.f);
    gemm_bt<<<dim3(1,8,1), blk, 0, stream>>>(kpeB, 0, WrcT, nullptr, pos_cb, 0, 1024, 1024, brc, 1.f);

    // attention
    attention<<<dim3(64,16,4), blk, 0, stream>>>(q_ws, k_comp, vcT, kwin, vwinT,
                                                 pos_cb, pos_tb, r_w, r_r, attn_o);
    // output projection (f32 out)
    gemm_bt<<<dim3(64,8,1), blk, 0, stream>>>(attn_o, 0, WoT, (float*)d_out, nullptr, 0, 1024, 1024, nullptr, 1.f);
}